// Round 3
// baseline (3858.323 us; speedup 1.0000x reference)
//
#include <hip/hip_runtime.h>
#include <cmath>

#define EPSF 1e-6f
#define TAUF 0.03f

// ---------- helpers ----------
__device__ inline float wred_sum(float v) {
    #pragma unroll
    for (int d = 1; d < 64; d <<= 1) v += __shfl_xor(v, d);
    return v;
}
__device__ inline float wred_max(float v) {
    #pragma unroll
    for (int d = 1; d < 64; d <<= 1) v = fmaxf(v, __shfl_xor(v, d));
    return v;
}

// ---------- K1: conv3x3 + bias + relu ----------
// grid (7 row-tiles, 4 oc-groups of 64, 32 batch), block 256
// out h1 layout: [b][p=784][oc=256]
__global__ __launch_bounds__(256) void conv3x3_relu_kernel(
    const float* __restrict__ feat, const float* __restrict__ w1,
    const float* __restrict__ b1, float* __restrict__ h1) {
    const int ty = blockIdx.x;   // 0..6  rows 4*ty..4*ty+3
    const int og = blockIdx.y;   // 0..3  oc 64*og..
    const int b  = blockIdx.z;
    const int tid = threadIdx.x;
    const int g = tid >> 4;        // pixel group 0..15
    const int q = tid & 15;        // oc quad 0..15
    const int r  = g >> 2;         // row in tile 0..3
    const int x0 = (g & 3) * 7;    // col start

    __shared__ float fs[4][6][32];   // [cb][halo row][halo col] (cols 0..29 valid)
    __shared__ float ws_[64][37];    // [oc][cb*9+tap], padded to 37 for banks

    float acc[4][7];
    #pragma unroll
    for (int o = 0; o < 4; ++o)
        #pragma unroll
        for (int px = 0; px < 7; ++px) acc[o][px] = 0.f;

    const int y_base = ty * 4 - 1;

    for (int cc = 0; cc < 256; ++cc) {
        const int c0 = cc * 4;
        // stage feat halo for 4 input channels: 4*6*32
        for (int idx = tid; idx < 768; idx += 256) {
            int cb = idx / 192; int rem = idx - cb * 192;
            int row = rem >> 5; int xi = rem & 31;
            int y = y_base + row; int x = xi - 1;
            float v = 0.f;
            if (xi < 30 && (unsigned)y < 28u && (unsigned)x < 28u)
                v = feat[(((size_t)b * 1024 + c0 + cb) * 28 + y) * 28 + x];
            fs[cb][row][xi] = v;
        }
        // stage weights: 64 oc x 36 (4c x 9 taps) contiguous per oc
        for (int idx = tid; idx < 2304; idx += 256) {
            int ocl = idx / 36; int t36 = idx - ocl * 36;
            ws_[ocl][t36] = w1[(size_t)(og * 64 + ocl) * 9216 + (size_t)c0 * 9 + t36];
        }
        __syncthreads();
        #pragma unroll
        for (int cb = 0; cb < 4; ++cb) {
            float f[3][9];
            #pragma unroll
            for (int dy = 0; dy < 3; ++dy)
                #pragma unroll
                for (int i = 0; i < 9; ++i) f[dy][i] = fs[cb][r + dy][x0 + i];
            #pragma unroll
            for (int o = 0; o < 4; ++o) {
                float w9[9];
                #pragma unroll
                for (int t = 0; t < 9; ++t) w9[t] = ws_[q * 4 + o][cb * 9 + t];
                #pragma unroll
                for (int px = 0; px < 7; ++px)
                    #pragma unroll
                    for (int ky = 0; ky < 3; ++ky)
                        #pragma unroll
                        for (int kx = 0; kx < 3; ++kx)
                            acc[o][px] += f[ky][px + kx] * w9[ky * 3 + kx];
            }
        }
        __syncthreads();
    }
    const int oc = og * 64 + q * 4;
    const float4 bv = *reinterpret_cast<const float4*>(&b1[oc]);
    const int prow = ty * 4 + r;
    #pragma unroll
    for (int px = 0; px < 7; ++px) {
        int p = prow * 28 + x0 + px;
        float4 o4;
        o4.x = fmaxf(acc[0][px] + bv.x, 0.f);
        o4.y = fmaxf(acc[1][px] + bv.y, 0.f);
        o4.z = fmaxf(acc[2][px] + bv.z, 0.f);
        o4.w = fmaxf(acc[3][px] + bv.w, 0.f);
        *reinterpret_cast<float4*>(&h1[((size_t)(b * 784 + p)) * 256 + oc]) = o4;
    }
}

// ---------- K2: 1x1 conv + prior + softmax + norms + coords + loss partials ----------
// grid 32 (one block per batch), block 256 (4 waves)
__global__ __launch_bounds__(256) void head_kernel(
    const float* __restrict__ h1, const float* __restrict__ w2,
    const float* __restrict__ b2, float* __restrict__ out,
    float* __restrict__ partials) {
    const int b = blockIdx.x;
    const int tid = threadIdx.x;
    const int lane = tid & 63;
    const int wv = tid >> 6;

    __shared__ float lg[12][784];     // logits -> probs (in place)
    __shared__ float w2s[12][256];
    __shared__ float kN[12], kE[12], cx_s[12], cy_s[12];
    __shared__ float redD[4];
    __shared__ float redS;

    for (int idx = tid; idx < 3072; idx += 256) w2s[idx >> 8][idx & 255] = w2[idx];
    float bias[12];
    #pragma unroll
    for (int k = 0; k < 12; ++k) bias[k] = b2[k];
    __syncthreads();

    // Phase B: logits + prior
    for (int p = tid; p < 784; p += 256) {
        float acc[12];
        #pragma unroll
        for (int k = 0; k < 12; ++k) acc[k] = bias[k];
        const float* hp = &h1[((size_t)(b * 784 + p)) * 256];
        for (int c = 0; c < 256; c += 4) {
            float4 hv = *reinterpret_cast<const float4*>(hp + c);
            #pragma unroll
            for (int k = 0; k < 12; ++k) {
                float4 wq = *reinterpret_cast<const float4*>(&w2s[k][c]);
                acc[k] += hv.x * wq.x + hv.y * wq.y + hv.z * wq.z + hv.w * wq.w;
            }
        }
        float gx = (float)(p % 28) * (1.f / 27.f);
        float gy = (float)(p / 28) * (1.f / 27.f);
        #pragma unroll
        for (int k = 0; k < 12; ++k) {
            float cxk = 0.15f + (0.7f / 3.f) * (float)(k & 3);
            float cyk = 0.15f + 0.35f * (float)(k >> 2);
            float dx = gx - cxk, dy = gy - cyk;
            float prior = -(dx * dx + dy * dy) / (2.f * 0.22f * 0.22f);
            lg[k][p] = acc[k] + 0.15f * prior;
        }
    }
    __syncthreads();

    // Phase C: temperature softmax over p, per k (each k owned by one wave)
    for (int k = wv; k < 12; k += 4) {
        float m = -1e30f;
        for (int p = lane; p < 784; p += 64) m = fmaxf(m, lg[k][p]);
        m = wred_max(m);
        float mz = m / TAUF;
        float s = 0.f;
        for (int p = lane; p < 784; p += 64) {
            float e = expf(lg[k][p] / TAUF - mz);
            lg[k][p] = e;
            s += e;
        }
        s = wred_sum(s);
        float inv = 1.f / s;
        for (int p = lane; p < 784; p += 64) lg[k][p] *= inv;
    }
    __syncthreads();

    // Phase D: normalize across K per pixel
    for (int p = tid; p < 784; p += 256) {
        float s12 = 0.f;
        #pragma unroll
        for (int k = 0; k < 12; ++k) s12 += lg[k][p];
        s12 += EPSF;
        float inv = 1.f / s12;
        #pragma unroll
        for (int k = 0; k < 12; ++k) lg[k][p] *= inv;
    }
    __syncthreads();

    // Phase E: spatial renorm, write probs, coords, entropy, norms
    for (int k = wv; k < 12; k += 4) {
        float S = 0.f;
        for (int p = lane; p < 784; p += 64) S += lg[k][p];
        S = wred_sum(S);
        float invS = 1.f / fmaxf(S, EPSF);
        float xs = 0.f, ys = 0.f, sp = 0.f, ent = 0.f, n2 = 0.f;
        for (int p = lane; p < 784; p += 64) {
            float v = lg[k][p] * invS;
            lg[k][p] = v;
            out[(size_t)b * 9408 + k * 784 + p] = v;
            float gx = (float)(p % 28) * (1.f / 27.f);
            float gy = (float)(p / 28) * (1.f / 27.f);
            xs += v * gx; ys += v * gy; sp += v;
            float vc = fmaxf(v, EPSF);
            ent -= vc * logf(vc);
            n2 += v * v;
        }
        xs = wred_sum(xs); ys = wred_sum(ys); sp = wred_sum(sp);
        ent = wred_sum(ent); n2 = wred_sum(n2);
        if (lane == 0) {
            float spc = fmaxf(sp, EPSF);
            float cx = xs / spc, cy = ys / spc;
            cx_s[k] = cx; cy_s[k] = cy;
            out[301056 + (size_t)b * 24 + 2 * k]     = cx;
            out[301056 + (size_t)b * 24 + 2 * k + 1] = cy;
            kN[k] = fmaxf(sqrtf(n2), EPSF);
            kE[k] = ent;
        }
    }
    __syncthreads();

    // Phase F: diversity pairs + separation
    float divp = 0.f;
    int pi = 0;
    for (int k = 0; k < 12; ++k) {
        for (int j = k + 1; j < 12; ++j) {
            if ((pi & 3) == wv) {
                float dot = 0.f;
                for (int p = lane; p < 784; p += 64) dot += lg[k][p] * lg[j][p];
                dot = wred_sum(dot);
                float simv = dot / (kN[k] * kN[j]);
                divp += 2.f * simv * simv;
            }
            ++pi;
        }
    }
    if (lane == 0) redD[wv] = divp;
    if (wv == 0) {
        float ssum = 0.f;
        for (int pr = lane; pr < 132; pr += 64) {
            int k = pr / 11; int jj = pr % 11; int j = jj + (jj >= k ? 1 : 0);
            float dx = cx_s[k] - cx_s[j], dy = cy_s[k] - cy_s[j];
            float d2 = dx * dx + dy * dy;
            float dist = sqrtf(fmaxf(d2, 1e-12f));
            ssum += 1.f / fmaxf(dist, EPSF);
        }
        ssum = wred_sum(ssum);
        if (lane == 0) redS = ssum;
    }
    __syncthreads();
    if (tid == 0) {
        float db = redD[0] + redD[1] + redD[2] + redD[3];
        float eb = 0.f;
        #pragma unroll
        for (int k = 0; k < 12; ++k) eb += kE[k];
        partials[b]      = db;
        partials[32 + b] = eb;
        partials[64 + b] = redS;
    }
}

// ---------- K3: feat_k = einsum('bcp,bkp->bkc')/784 ----------
// grid (4 c-groups, 32 batch), block 256
__global__ __launch_bounds__(256) void featk_kernel(
    const float* __restrict__ feat, const float* __restrict__ probs,
    float* __restrict__ outfk) {
    const int cg = blockIdx.x, b = blockIdx.y;
    const int tid = threadIdx.x;
    __shared__ float ps[12 * 784];
    for (int idx = tid; idx < 9408; idx += 256) ps[idx] = probs[(size_t)b * 9408 + idx];
    __syncthreads();
    const int c = cg * 256 + tid;
    const float* fp = &feat[((size_t)b * 1024 + c) * 784];
    float acc[12];
    #pragma unroll
    for (int k = 0; k < 12; ++k) acc[k] = 0.f;
    for (int pc = 0; pc < 784; pc += 4) {
        float4 f4 = *reinterpret_cast<const float4*>(fp + pc);
        #pragma unroll
        for (int k = 0; k < 12; ++k) {
            float4 p4 = *reinterpret_cast<const float4*>(&ps[k * 784 + pc]);
            acc[k] += f4.x * p4.x + f4.y * p4.y + f4.z * p4.z + f4.w * p4.w;
        }
    }
    #pragma unroll
    for (int k = 0; k < 12; ++k)
        outfk[(size_t)b * 12288 + k * 1024 + c] = acc[k] * (1.f / 784.f);
}

// ---------- K4: reduce loss partials ----------
__global__ void finalize_kernel(const float* __restrict__ part, float* __restrict__ out) {
    int t = threadIdx.x;
    float d = t < 32 ? part[t]      : 0.f;
    float e = t < 32 ? part[32 + t] : 0.f;
    float s = t < 32 ? part[64 + t] : 0.f;
    d = wred_sum(d); e = wred_sum(e); s = wred_sum(s);
    if (t == 0) {
        out[695040] = d / 4608.f;                 // mean over 32*12*12
        out[695041] = e / 384.f;                  // mean over 32*12
        out[695042] = s / (4224.f + 1e-6f);       // /(b*k*(k-1)+eps)
    }
}

extern "C" void kernel_launch(void* const* d_in, const int* in_sizes, int n_in,
                              void* d_out, int out_size, void* d_ws, size_t ws_size,
                              hipStream_t stream) {
    const float* feat = (const float*)d_in[0];
    const float* w1   = (const float*)d_in[1];
    const float* b1   = (const float*)d_in[2];
    const float* w2   = (const float*)d_in[3];
    const float* b2   = (const float*)d_in[4];
    float* out = (float*)d_out;
    float* h1  = (float*)d_ws;                  // 32*784*256 floats = 25.7 MB
    float* part = h1 + (size_t)32 * 784 * 256;  // 96 floats of loss partials

    conv3x3_relu_kernel<<<dim3(7, 4, 32), 256, 0, stream>>>(feat, w1, b1, h1);
    head_kernel<<<dim3(32), 256, 0, stream>>>(h1, w2, b2, out, part);
    featk_kernel<<<dim3(4, 32), 256, 0, stream>>>(feat, out, out + 301824);
    finalize_kernel<<<dim3(1), 64, 0, stream>>>(part, out);
}

// Round 4
// 608.732 us; speedup vs baseline: 6.3383x; 6.3383x over previous
//
#include <hip/hip_runtime.h>
#include <cmath>

#define EPSF 1e-6f
#define TAUF 0.03f

typedef short bf16x8 __attribute__((ext_vector_type(8)));
typedef float f32x4 __attribute__((ext_vector_type(4)));

// ---------- helpers ----------
__device__ inline float wred_sum(float v) {
    #pragma unroll
    for (int d = 1; d < 64; d <<= 1) v += __shfl_xor(v, d);
    return v;
}
__device__ inline float wred_max(float v) {
    #pragma unroll
    for (int d = 1; d < 64; d <<= 1) v = fmaxf(v, __shfl_xor(v, d));
    return v;
}
__device__ inline short f2bf(float f) {
    unsigned u = __float_as_uint(f);
    unsigned lsb = (u >> 16) & 1u;
    u += 0x7fffu + lsb;
    return (short)(u >> 16);
}
__device__ inline float bf2f(short h) {
    return __uint_as_float(((unsigned)(unsigned short)h) << 16);
}
__device__ __forceinline__ void gld16(const void* g, void* l) {
    __builtin_amdgcn_global_load_lds(
        (const __attribute__((address_space(1))) unsigned int*)g,
        (__attribute__((address_space(3))) unsigned int*)l, 16, 0, 0);
}

// =================== pre-pass: weight conversion ===================
// w1 [256 oc][1024 c][3][3] fp32 -> B_hi/B_lo [tap][oc][c] bf16
__global__ __launch_bounds__(256) void cvt_w1_kernel(
    const float* __restrict__ w1, short* __restrict__ B_hi, short* __restrict__ B_lo) {
    int idx = blockIdx.x * 256 + threadIdx.x;   // 0..262143 = (oc, c)
    int oc = idx >> 10, c = idx & 1023;
    const float* wp = w1 + (size_t)oc * 9216 + c * 9;
    #pragma unroll
    for (int t = 0; t < 9; ++t) {
        float f = wp[t];
        short h = f2bf(f);
        short lo = f2bf(f - bf2f(h));
        size_t o = (size_t)t * 262144 + oc * 1024 + c;
        B_hi[o] = h; B_lo[o] = lo;
    }
}

// =================== pre-pass: feature conversion ===================
// feat [b][c][28][28] fp32 -> A_hi/A_lo [b][30 rows (y+1)][32 cols (x+1)][1024 c] bf16
// guard rows 0,29 and pad cols 0,29..31 are pre-zeroed by memset.
__global__ __launch_bounds__(256) void cvt_feat_kernel(
    const float* __restrict__ feat, short* __restrict__ A_hi, short* __restrict__ A_lo) {
    const int cg = blockIdx.x;   // 0..3
    const int y  = blockIdx.y;   // 0..27
    const int b  = blockIdx.z;
    const int tid = threadIdx.x;
    __shared__ float tile[256][29];
    const int c = cg * 256 + tid;
    const float* fp = feat + ((size_t)(b * 1024 + c) * 28 + y) * 28;
    #pragma unroll
    for (int j = 0; j < 7; ++j) {
        float4 v = *reinterpret_cast<const float4*>(fp + 4 * j);
        tile[tid][4 * j + 0] = v.x; tile[tid][4 * j + 1] = v.y;
        tile[tid][4 * j + 2] = v.z; tile[tid][4 * j + 3] = v.w;
    }
    __syncthreads();
    size_t base = ((size_t)(b * 30 + y + 1) * 32) * 1024 + cg * 256 + tid;
    #pragma unroll
    for (int j = 0; j < 28; ++j) {
        float v = tile[tid][j];          // feat[b][c][y][j] with c = cg*256+tid
        short h = f2bf(v);
        short lo = f2bf(v - bf2f(h));
        size_t o = base + (size_t)(j + 1) * 1024;
        A_hi[o] = h; A_lo[o] = lo;
    }
}

// =================== K1: conv3x3 via split-bf16 MFMA ===================
// grid (7 ty, 2 og, 32 b), 256 thr (4 waves). C tile 112x128, K chunks of 32 ch, 9 taps.
__global__ __launch_bounds__(256) void conv_mfma_kernel(
    const short* __restrict__ A_hi, const short* __restrict__ A_lo,
    const short* __restrict__ B_hi, const short* __restrict__ B_lo,
    const float* __restrict__ b1, float* __restrict__ h1) {
    const int ty = blockIdx.x;    // 0..6
    const int og = blockIdx.y;    // 0..1
    const int b  = blockIdx.z;
    const int tid = threadIdx.x;
    const int lane = tid & 63, wv = tid >> 6;
    const int l15 = lane & 15, sub0 = lane >> 4;

    __shared__ __align__(16) short AsH[6144];     // [6 rows][32 cols][32 ch]
    __shared__ __align__(16) short AsL[6144];
    __shared__ __align__(16) short Bs[2][8192];   // per buf: hi[128 oc][32 k] then lo

    // staging source element-offsets (A: 3 chunks per array; B: 4 chunks)
    int a_src[3];
    #pragma unroll
    for (int j = 0; j < 3; ++j) {
        int q = tid + 256 * j;              // 0..767
        int cell = q >> 2, sub = q & 3;
        int row = cell >> 5, col = cell & 31;
        a_src[j] = ((b * 30 + 4 * ty + row) * 32 + col) * 1024 + 8 * (sub ^ ((col >> 1) & 3));
    }
    int b_src[4]; const short* b_base[4];
    #pragma unroll
    for (int i = 0; i < 4; ++i) {
        int q = tid + 256 * i;              // 0..1023
        int arr = q >> 9, sub = q & 3;
        int oc_l = (q >> 2) & 127;
        b_src[i] = (og * 128 + oc_l) * 1024 + 8 * (sub ^ ((oc_l >> 1) & 3));
        b_base[i] = arr ? B_lo : B_hi;
    }
    // fragment read offsets
    int rowb[7], colb[7][3];
    #pragma unroll
    for (int f = 0; f < 7; ++f) {
        int m = 16 * f + l15;
        int yl = m / 28, x = m % 28;
        rowb[f] = yl * 2048;
        #pragma unroll
        for (int kx = 0; kx < 3; ++kx) {
            int cc = x + kx;
            colb[f][kx] = cc * 64 + ((sub0 ^ ((cc >> 1) & 3)) << 4);
        }
    }
    int boff[2];
    #pragma unroll
    for (int n = 0; n < 2; ++n) {
        int oc_l = 32 * wv + 16 * n + l15;
        boff[n] = oc_l * 64 + ((sub0 ^ ((oc_l >> 1) & 3)) << 4);
    }

    f32x4 acc[7][2];
    #pragma unroll
    for (int f = 0; f < 7; ++f)
        #pragma unroll
        for (int n = 0; n < 2; ++n) acc[f][n] = (f32x4){0.f, 0.f, 0.f, 0.f};

    for (int c0 = 0; c0 < 1024; c0 += 32) {
        // stage A hi+lo (3 chunks each) and B tap0 -> buf0
        #pragma unroll
        for (int j = 0; j < 3; ++j) {
            gld16(A_hi + a_src[j] + c0, (char*)AsH + (tid + 256 * j) * 16);
            gld16(A_lo + a_src[j] + c0, (char*)AsL + (tid + 256 * j) * 16);
        }
        #pragma unroll
        for (int i = 0; i < 4; ++i)
            gld16(b_base[i] + b_src[i] + c0, (char*)Bs[0] + (tid + 256 * i) * 16);
        __syncthreads();

        for (int tap = 0; tap < 9; ++tap) {
            int buf = tap & 1;
            if (tap < 8) {  // prefetch next tap's B into other buffer
                #pragma unroll
                for (int i = 0; i < 4; ++i)
                    gld16(b_base[i] + b_src[i] + (tap + 1) * 262144 + c0,
                          (char*)Bs[buf ^ 1] + (tid + 256 * i) * 16);
            }
            int ky = tap / 3, kx = tap - 3 * ky;
            bf16x8 ah[7], al[7];
            #pragma unroll
            for (int f = 0; f < 7; ++f) {
                int off = rowb[f] + ky * 2048 + colb[f][kx];
                ah[f] = *(const bf16x8*)((const char*)AsH + off);
                al[f] = *(const bf16x8*)((const char*)AsL + off);
            }
            bf16x8 bh[2], bl[2];
            #pragma unroll
            for (int n = 0; n < 2; ++n) {
                bh[n] = *(const bf16x8*)((const char*)Bs[buf] + boff[n]);
                bl[n] = *(const bf16x8*)((const char*)Bs[buf] + 8192 + boff[n]);
            }
            #pragma unroll
            for (int f = 0; f < 7; ++f)
                #pragma unroll
                for (int n = 0; n < 2; ++n) {
                    acc[f][n] = __builtin_amdgcn_mfma_f32_16x16x32_bf16(ah[f], bh[n], acc[f][n], 0, 0, 0);
                    acc[f][n] = __builtin_amdgcn_mfma_f32_16x16x32_bf16(ah[f], bl[n], acc[f][n], 0, 0, 0);
                    acc[f][n] = __builtin_amdgcn_mfma_f32_16x16x32_bf16(al[f], bh[n], acc[f][n], 0, 0, 0);
                }
            __syncthreads();
        }
    }
    // epilogue: bias + relu, h1[b][p][oc]
    #pragma unroll
    for (int n = 0; n < 2; ++n) {
        int oc = og * 128 + 32 * wv + 16 * n + l15;
        float bias = b1[oc];
        #pragma unroll
        for (int f = 0; f < 7; ++f) {
            #pragma unroll
            for (int r = 0; r < 4; ++r) {
                int p = ty * 112 + 16 * f + 4 * sub0 + r;
                h1[((size_t)(b * 784 + p)) * 256 + oc] = fmaxf(acc[f][n][r] + bias, 0.f);
            }
        }
    }
}

// =================== K2a: 1x1 conv logits + prior ===================
// grid (7, 32), 128 thr; logits[b][k][p]
__global__ __launch_bounds__(128) void logits_kernel(
    const float* __restrict__ h1, const float* __restrict__ w2,
    const float* __restrict__ b2, float* __restrict__ logits) {
    const int b = blockIdx.y;
    const int tid = threadIdx.x;
    __shared__ float w2s[12][256];
    for (int i = tid; i < 3072; i += 128) w2s[i >> 8][i & 255] = w2[i];
    __syncthreads();
    if (tid < 112) {
        int p = blockIdx.x * 112 + tid;
        float acc[12];
        #pragma unroll
        for (int k = 0; k < 12; ++k) acc[k] = b2[k];
        const float* hp = h1 + ((size_t)(b * 784 + p)) * 256;
        for (int c = 0; c < 256; c += 4) {
            float4 hv = *reinterpret_cast<const float4*>(hp + c);
            #pragma unroll
            for (int k = 0; k < 12; ++k) {
                float4 wq = *reinterpret_cast<const float4*>(&w2s[k][c]);
                acc[k] += hv.x * wq.x + hv.y * wq.y + hv.z * wq.z + hv.w * wq.w;
            }
        }
        float gx = (float)(p % 28) * (1.f / 27.f);
        float gy = (float)(p / 28) * (1.f / 27.f);
        #pragma unroll
        for (int k = 0; k < 12; ++k) {
            float cxk = 0.15f + (0.7f / 3.f) * (float)(k & 3);
            float cyk = 0.15f + 0.35f * (float)(k >> 2);
            float dx = gx - cxk, dy = gy - cyk;
            float prior = -(dx * dx + dy * dy) / (2.f * 0.22f * 0.22f);
            logits[(size_t)b * 9408 + k * 784 + p] = acc[k] + 0.15f * prior;
        }
    }
}

// =================== K2b: softmax + norms + coords + loss partials ===================
__global__ __launch_bounds__(256) void head2_kernel(
    const float* __restrict__ logits, float* __restrict__ out,
    float* __restrict__ partials) {
    const int b = blockIdx.x;
    const int tid = threadIdx.x;
    const int lane = tid & 63;
    const int wv = tid >> 6;

    __shared__ float lg[12][784];
    __shared__ float kN[12], kE[12], cx_s[12], cy_s[12];
    __shared__ float redD[4];
    __shared__ float redS;

    for (int idx = tid; idx < 9408; idx += 256)
        ((float*)lg)[idx] = logits[(size_t)b * 9408 + idx];
    __syncthreads();

    // temperature softmax per k
    for (int k = wv; k < 12; k += 4) {
        float m = -1e30f;
        for (int p = lane; p < 784; p += 64) m = fmaxf(m, lg[k][p]);
        m = wred_max(m);
        float mz = m / TAUF;
        float s = 0.f;
        for (int p = lane; p < 784; p += 64) {
            float e = expf(lg[k][p] / TAUF - mz);
            lg[k][p] = e;
            s += e;
        }
        s = wred_sum(s);
        float inv = 1.f / s;
        for (int p = lane; p < 784; p += 64) lg[k][p] *= inv;
    }
    __syncthreads();

    // cross-K normalize per pixel
    for (int p = tid; p < 784; p += 256) {
        float s12 = 0.f;
        #pragma unroll
        for (int k = 0; k < 12; ++k) s12 += lg[k][p];
        s12 += EPSF;
        float inv = 1.f / s12;
        #pragma unroll
        for (int k = 0; k < 12; ++k) lg[k][p] *= inv;
    }
    __syncthreads();

    // spatial renorm, probs out, coords, entropy, norms
    for (int k = wv; k < 12; k += 4) {
        float S = 0.f;
        for (int p = lane; p < 784; p += 64) S += lg[k][p];
        S = wred_sum(S);
        float invS = 1.f / fmaxf(S, EPSF);
        float xs = 0.f, ys = 0.f, sp = 0.f, ent = 0.f, n2 = 0.f;
        for (int p = lane; p < 784; p += 64) {
            float v = lg[k][p] * invS;
            lg[k][p] = v;
            out[(size_t)b * 9408 + k * 784 + p] = v;
            float gx = (float)(p % 28) * (1.f / 27.f);
            float gy = (float)(p / 28) * (1.f / 27.f);
            xs += v * gx; ys += v * gy; sp += v;
            float vc = fmaxf(v, EPSF);
            ent -= vc * logf(vc);
            n2 += v * v;
        }
        xs = wred_sum(xs); ys = wred_sum(ys); sp = wred_sum(sp);
        ent = wred_sum(ent); n2 = wred_sum(n2);
        if (lane == 0) {
            float spc = fmaxf(sp, EPSF);
            float cx = xs / spc, cy = ys / spc;
            cx_s[k] = cx; cy_s[k] = cy;
            out[301056 + (size_t)b * 24 + 2 * k]     = cx;
            out[301056 + (size_t)b * 24 + 2 * k + 1] = cy;
            kN[k] = fmaxf(sqrtf(n2), EPSF);
            kE[k] = ent;
        }
    }
    __syncthreads();

    // diversity + separation
    float divp = 0.f;
    int pi = 0;
    for (int k = 0; k < 12; ++k) {
        for (int j = k + 1; j < 12; ++j) {
            if ((pi & 3) == wv) {
                float dot = 0.f;
                for (int p = lane; p < 784; p += 64) dot += lg[k][p] * lg[j][p];
                dot = wred_sum(dot);
                float simv = dot / (kN[k] * kN[j]);
                divp += 2.f * simv * simv;
            }
            ++pi;
        }
    }
    if (lane == 0) redD[wv] = divp;
    if (wv == 0) {
        float ssum = 0.f;
        for (int pr = lane; pr < 132; pr += 64) {
            int k = pr / 11; int jj = pr % 11; int j = jj + (jj >= k ? 1 : 0);
            float dx = cx_s[k] - cx_s[j], dy = cy_s[k] - cy_s[j];
            float d2 = dx * dx + dy * dy;
            float dist = sqrtf(fmaxf(d2, 1e-12f));
            ssum += 1.f / fmaxf(dist, EPSF);
        }
        ssum = wred_sum(ssum);
        if (lane == 0) redS = ssum;
    }
    __syncthreads();
    if (tid == 0) {
        float db = redD[0] + redD[1] + redD[2] + redD[3];
        float eb = 0.f;
        #pragma unroll
        for (int k = 0; k < 12; ++k) eb += kE[k];
        partials[b]      = db;
        partials[32 + b] = eb;
        partials[64 + b] = redS;
    }
}

// =================== K3: feat_k einsum ===================
// grid (8, 32), 128 thr
__global__ __launch_bounds__(128) void featk2_kernel(
    const float* __restrict__ feat, const float* __restrict__ probs,
    float* __restrict__ outfk) {
    const int cg = blockIdx.x, b = blockIdx.y;
    const int tid = threadIdx.x;
    __shared__ float ps[12 * 784];
    for (int idx = tid; idx < 9408; idx += 128) ps[idx] = probs[(size_t)b * 9408 + idx];
    __syncthreads();
    const int c = cg * 128 + tid;
    const float* fp = &feat[((size_t)b * 1024 + c) * 784];
    float acc[12];
    #pragma unroll
    for (int k = 0; k < 12; ++k) acc[k] = 0.f;
    for (int pc = 0; pc < 784; pc += 4) {
        float4 f4 = *reinterpret_cast<const float4*>(fp + pc);
        #pragma unroll
        for (int k = 0; k < 12; ++k) {
            float4 p4 = *reinterpret_cast<const float4*>(&ps[k * 784 + pc]);
            acc[k] += f4.x * p4.x + f4.y * p4.y + f4.z * p4.z + f4.w * p4.w;
        }
    }
    #pragma unroll
    for (int k = 0; k < 12; ++k)
        outfk[(size_t)b * 12288 + k * 1024 + c] = acc[k] * (1.f / 784.f);
}

// =================== K4: reduce partials ===================
__global__ void finalize_kernel(const float* __restrict__ part, float* __restrict__ out) {
    int t = threadIdx.x;
    float d = t < 32 ? part[t]      : 0.f;
    float e = t < 32 ? part[32 + t] : 0.f;
    float s = t < 32 ? part[64 + t] : 0.f;
    d = wred_sum(d); e = wred_sum(e); s = wred_sum(s);
    if (t == 0) {
        out[695040] = d / 4608.f;
        out[695041] = e / 384.f;
        out[695042] = s / (4224.f + 1e-6f);
    }
}

// =================== fallback fp32 path (round-0, verified) ===================
__global__ __launch_bounds__(256) void conv3x3_relu_kernel(
    const float* __restrict__ feat, const float* __restrict__ w1,
    const float* __restrict__ b1, float* __restrict__ h1) {
    const int ty = blockIdx.x;
    const int og = blockIdx.y;
    const int b  = blockIdx.z;
    const int tid = threadIdx.x;
    const int g = tid >> 4;
    const int q = tid & 15;
    const int r  = g >> 2;
    const int x0 = (g & 3) * 7;
    __shared__ float fs[4][6][32];
    __shared__ float ws_[64][37];
    float acc[4][7];
    #pragma unroll
    for (int o = 0; o < 4; ++o)
        #pragma unroll
        for (int px = 0; px < 7; ++px) acc[o][px] = 0.f;
    const int y_base = ty * 4 - 1;
    for (int cc = 0; cc < 256; ++cc) {
        const int c0 = cc * 4;
        for (int idx = tid; idx < 768; idx += 256) {
            int cb = idx / 192; int rem = idx - cb * 192;
            int row = rem >> 5; int xi = rem & 31;
            int y = y_base + row; int x = xi - 1;
            float v = 0.f;
            if (xi < 30 && (unsigned)y < 28u && (unsigned)x < 28u)
                v = feat[(((size_t)b * 1024 + c0 + cb) * 28 + y) * 28 + x];
            fs[cb][row][xi] = v;
        }
        for (int idx = tid; idx < 2304; idx += 256) {
            int ocl = idx / 36; int t36 = idx - ocl * 36;
            ws_[ocl][t36] = w1[(size_t)(og * 64 + ocl) * 9216 + (size_t)c0 * 9 + t36];
        }
        __syncthreads();
        #pragma unroll
        for (int cb = 0; cb < 4; ++cb) {
            float f[3][9];
            #pragma unroll
            for (int dy = 0; dy < 3; ++dy)
                #pragma unroll
                for (int i = 0; i < 9; ++i) f[dy][i] = fs[cb][r + dy][x0 + i];
            #pragma unroll
            for (int o = 0; o < 4; ++o) {
                float w9[9];
                #pragma unroll
                for (int t = 0; t < 9; ++t) w9[t] = ws_[q * 4 + o][cb * 9 + t];
                #pragma unroll
                for (int px = 0; px < 7; ++px)
                    #pragma unroll
                    for (int ky = 0; ky < 3; ++ky)
                        #pragma unroll
                        for (int kx = 0; kx < 3; ++kx)
                            acc[o][px] += f[ky][px + kx] * w9[ky * 3 + kx];
            }
        }
        __syncthreads();
    }
    const int oc = og * 64 + q * 4;
    const float4 bv = *reinterpret_cast<const float4*>(&b1[oc]);
    const int prow = ty * 4 + r;
    #pragma unroll
    for (int px = 0; px < 7; ++px) {
        int p = prow * 28 + x0 + px;
        float4 o4;
        o4.x = fmaxf(acc[0][px] + bv.x, 0.f);
        o4.y = fmaxf(acc[1][px] + bv.y, 0.f);
        o4.z = fmaxf(acc[2][px] + bv.z, 0.f);
        o4.w = fmaxf(acc[3][px] + bv.w, 0.f);
        *reinterpret_cast<float4*>(&h1[((size_t)(b * 784 + p)) * 256 + oc]) = o4;
    }
}

__global__ __launch_bounds__(256) void head_kernel(
    const float* __restrict__ h1, const float* __restrict__ w2,
    const float* __restrict__ b2, float* __restrict__ out,
    float* __restrict__ partials) {
    const int b = blockIdx.x;
    const int tid = threadIdx.x;
    const int lane = tid & 63;
    const int wv = tid >> 6;
    __shared__ float lg[12][784];
    __shared__ float w2s[12][256];
    __shared__ float kN[12], kE[12], cx_s[12], cy_s[12];
    __shared__ float redD[4];
    __shared__ float redS;
    for (int idx = tid; idx < 3072; idx += 256) w2s[idx >> 8][idx & 255] = w2[idx];
    float bias[12];
    #pragma unroll
    for (int k = 0; k < 12; ++k) bias[k] = b2[k];
    __syncthreads();
    for (int p = tid; p < 784; p += 256) {
        float acc[12];
        #pragma unroll
        for (int k = 0; k < 12; ++k) acc[k] = bias[k];
        const float* hp = &h1[((size_t)(b * 784 + p)) * 256];
        for (int c = 0; c < 256; c += 4) {
            float4 hv = *reinterpret_cast<const float4*>(hp + c);
            #pragma unroll
            for (int k = 0; k < 12; ++k) {
                float4 wq = *reinterpret_cast<const float4*>(&w2s[k][c]);
                acc[k] += hv.x * wq.x + hv.y * wq.y + hv.z * wq.z + hv.w * wq.w;
            }
        }
        float gx = (float)(p % 28) * (1.f / 27.f);
        float gy = (float)(p / 28) * (1.f / 27.f);
        #pragma unroll
        for (int k = 0; k < 12; ++k) {
            float cxk = 0.15f + (0.7f / 3.f) * (float)(k & 3);
            float cyk = 0.15f + 0.35f * (float)(k >> 2);
            float dx = gx - cxk, dy = gy - cyk;
            float prior = -(dx * dx + dy * dy) / (2.f * 0.22f * 0.22f);
            lg[k][p] = acc[k] + 0.15f * prior;
        }
    }
    __syncthreads();
    for (int k = wv; k < 12; k += 4) {
        float m = -1e30f;
        for (int p = lane; p < 784; p += 64) m = fmaxf(m, lg[k][p]);
        m = wred_max(m);
        float mz = m / TAUF;
        float s = 0.f;
        for (int p = lane; p < 784; p += 64) {
            float e = expf(lg[k][p] / TAUF - mz);
            lg[k][p] = e;
            s += e;
        }
        s = wred_sum(s);
        float inv = 1.f / s;
        for (int p = lane; p < 784; p += 64) lg[k][p] *= inv;
    }
    __syncthreads();
    for (int p = tid; p < 784; p += 256) {
        float s12 = 0.f;
        #pragma unroll
        for (int k = 0; k < 12; ++k) s12 += lg[k][p];
        s12 += EPSF;
        float inv = 1.f / s12;
        #pragma unroll
        for (int k = 0; k < 12; ++k) lg[k][p] *= inv;
    }
    __syncthreads();
    for (int k = wv; k < 12; k += 4) {
        float S = 0.f;
        for (int p = lane; p < 784; p += 64) S += lg[k][p];
        S = wred_sum(S);
        float invS = 1.f / fmaxf(S, EPSF);
        float xs = 0.f, ys = 0.f, sp = 0.f, ent = 0.f, n2 = 0.f;
        for (int p = lane; p < 784; p += 64) {
            float v = lg[k][p] * invS;
            lg[k][p] = v;
            out[(size_t)b * 9408 + k * 784 + p] = v;
            float gx = (float)(p % 28) * (1.f / 27.f);
            float gy = (float)(p / 28) * (1.f / 27.f);
            xs += v * gx; ys += v * gy; sp += v;
            float vc = fmaxf(v, EPSF);
            ent -= vc * logf(vc);
            n2 += v * v;
        }
        xs = wred_sum(xs); ys = wred_sum(ys); sp = wred_sum(sp);
        ent = wred_sum(ent); n2 = wred_sum(n2);
        if (lane == 0) {
            float spc = fmaxf(sp, EPSF);
            float cx = xs / spc, cy = ys / spc;
            cx_s[k] = cx; cy_s[k] = cy;
            out[301056 + (size_t)b * 24 + 2 * k]     = cx;
            out[301056 + (size_t)b * 24 + 2 * k + 1] = cy;
            kN[k] = fmaxf(sqrtf(n2), EPSF);
            kE[k] = ent;
        }
    }
    __syncthreads();
    float divp = 0.f;
    int pi = 0;
    for (int k = 0; k < 12; ++k) {
        for (int j = k + 1; j < 12; ++j) {
            if ((pi & 3) == wv) {
                float dot = 0.f;
                for (int p = lane; p < 784; p += 64) dot += lg[k][p] * lg[j][p];
                dot = wred_sum(dot);
                float simv = dot / (kN[k] * kN[j]);
                divp += 2.f * simv * simv;
            }
            ++pi;
        }
    }
    if (lane == 0) redD[wv] = divp;
    if (wv == 0) {
        float ssum = 0.f;
        for (int pr = lane; pr < 132; pr += 64) {
            int k = pr / 11; int jj = pr % 11; int j = jj + (jj >= k ? 1 : 0);
            float dx = cx_s[k] - cx_s[j], dy = cy_s[k] - cy_s[j];
            float d2 = dx * dx + dy * dy;
            float dist = sqrtf(fmaxf(d2, 1e-12f));
            ssum += 1.f / fmaxf(dist, EPSF);
        }
        ssum = wred_sum(ssum);
        if (lane == 0) redS = ssum;
    }
    __syncthreads();
    if (tid == 0) {
        float db = redD[0] + redD[1] + redD[2] + redD[3];
        float eb = 0.f;
        #pragma unroll
        for (int k = 0; k < 12; ++k) eb += kE[k];
        partials[b]      = db;
        partials[32 + b] = eb;
        partials[64 + b] = redS;
    }
}

__global__ __launch_bounds__(256) void featk_kernel(
    const float* __restrict__ feat, const float* __restrict__ probs,
    float* __restrict__ outfk) {
    const int cg = blockIdx.x, b = blockIdx.y;
    const int tid = threadIdx.x;
    __shared__ float ps[12 * 784];
    for (int idx = tid; idx < 9408; idx += 256) ps[idx] = probs[(size_t)b * 9408 + idx];
    __syncthreads();
    const int c = cg * 256 + tid;
    const float* fp = &feat[((size_t)b * 1024 + c) * 784];
    float acc[12];
    #pragma unroll
    for (int k = 0; k < 12; ++k) acc[k] = 0.f;
    for (int pc = 0; pc < 784; pc += 4) {
        float4 f4 = *reinterpret_cast<const float4*>(fp + pc);
        #pragma unroll
        for (int k = 0; k < 12; ++k) {
            float4 p4 = *reinterpret_cast<const float4*>(&ps[k * 784 + pc]);
            acc[k] += f4.x * p4.x + f4.y * p4.y + f4.z * p4.z + f4.w * p4.w;
        }
    }
    #pragma unroll
    for (int k = 0; k < 12; ++k)
        outfk[(size_t)b * 12288 + k * 1024 + c] = acc[k] * (1.f / 784.f);
}

// =================== launch ===================
extern "C" void kernel_launch(void* const* d_in, const int* in_sizes, int n_in,
                              void* d_out, int out_size, void* d_ws, size_t ws_size,
                              hipStream_t stream) {
    const float* feat = (const float*)d_in[0];
    const float* w1   = (const float*)d_in[1];
    const float* b1   = (const float*)d_in[2];
    const float* w2   = (const float*)d_in[3];
    const float* b2   = (const float*)d_in[4];
    float* out = (float*)d_out;

    // ws layout
    float* h1     = (float*)d_ws;                  // 6,422,528 f
    float* logits = h1 + 6422528;                  // 301,056 f
    float* part   = logits + 301056;               // 96 f (pad to 128)
    short* A_hi   = (short*)((char*)d_ws + 26894848);
    short* A_lo   = A_hi + 31457280;
    short* B_hi   = A_lo + 31457280;
    short* B_lo   = B_hi + 2359296;
    const size_t NEED = 162161152;

    if (ws_size >= NEED) {
        hipMemsetAsync(A_hi, 0, (size_t)31457280 * 2, stream);
        hipMemsetAsync(A_lo, 0, (size_t)31457280 * 2, stream);
        cvt_w1_kernel<<<1024, 256, 0, stream>>>(w1, B_hi, B_lo);
        cvt_feat_kernel<<<dim3(4, 28, 32), 256, 0, stream>>>(feat, A_hi, A_lo);
        conv_mfma_kernel<<<dim3(7, 2, 32), 256, 0, stream>>>(A_hi, A_lo, B_hi, B_lo, b1, h1);
        logits_kernel<<<dim3(7, 32), 128, 0, stream>>>(h1, w2, b2, logits);
        head2_kernel<<<32, 256, 0, stream>>>(logits, out, part);
        featk2_kernel<<<dim3(8, 32), 128, 0, stream>>>(feat, out, out + 301824);
        finalize_kernel<<<1, 64, 0, stream>>>(part, out);
    } else {
        conv3x3_relu_kernel<<<dim3(7, 4, 32), 256, 0, stream>>>(feat, w1, b1, h1);
        head_kernel<<<32, 256, 0, stream>>>(h1, w2, b2, out, part);
        featk_kernel<<<dim3(4, 32), 256, 0, stream>>>(feat, out, out + 301824);
        finalize_kernel<<<1, 64, 0, stream>>>(part, out);
    }
}